// Round 5
// baseline (381.075 us; speedup 1.0000x reference)
//
#include <hip/hip_runtime.h>
#include <hip/hip_bf16.h>
#include <cmath>

typedef __bf16 bf16_t;
typedef __bf16 bf16x8 __attribute__((ext_vector_type(8)));
typedef float  f32x4  __attribute__((ext_vector_type(4)));

#define AS1(p) ((__attribute__((address_space(1))) void*)(p))
#define AS3(p) ((__attribute__((address_space(3))) void*)(p))

// N=8192, H=512, TAU=0.5, EPS=1e-8
// exp(x) = exp2(x * log2e / TAU); (1/0.5)*log2e = 2.885390...
#define C_EXP2 2.8853900817779268f
#define NROWS  8192
#define HDIM   512

// ---------------------------------------------------------------- f32->bf16
__global__ __launch_bounds__(256) void cvt_f32_bf16(const float* __restrict__ src,
                                                    bf16_t* __restrict__ dst, int n8) {
    int i = blockIdx.x * 256 + threadIdx.x;
    if (i >= n8) return;
    const f32x4* s4 = (const f32x4*)src;
    f32x4 a = s4[2 * (size_t)i];
    f32x4 b = s4[2 * (size_t)i + 1];
    bf16x8 o;
#pragma unroll
    for (int j = 0; j < 4; ++j) { o[j] = (bf16_t)a[j]; o[4 + j] = (bf16_t)b[j]; }
    *(bf16x8*)(dst + 8 * (size_t)i) = o;
}

// ---------------------------------------------------------------- GEMM (NT)
// C[i][j] = sum_k A[i*K+k] * B[j*K+k], K=512. 128x128 tile, BK=32, NT=16,
// 2-deep dbuf (32 KB LDS -> 4 blocks/CU), fully-unrolled pipeline,
// raw s_barrier + counted vmcnt:
//   step t: stage(t+1) [4 loads] | pos row t [4 loads, EPI3] | ds_read+16 MFMA
//           | vmcnt(4): stage drained, pos floats across barrier | s_barrier
// LDS XOR swizzle: 4x16B chunks/row, chunk ^= row&3 -> balanced banks.
// EPI=1: bias+ELU -> bf16   EPI=2: bias -> f32 (d_out) + bf16 copy
// EPI=3: e=exp2(acc*rn0*rn1*C); row partial sums of e, e*pos -> pS/pP
template <int EPI>
__global__ __launch_bounds__(256, 4)
void gemm_bt(const bf16_t* __restrict__ A, const bf16_t* __restrict__ B,
             const float* __restrict__ bias,
             bf16_t* __restrict__ outb, float* __restrict__ outf,
             const float* __restrict__ rn0, const float* __restrict__ rn1,
             const float* __restrict__ pos,
             float* __restrict__ pS, float* __restrict__ pP) {
    constexpr int K  = 512;
    constexpr int NT = 16;
    __shared__ __align__(16) bf16_t As[2][128 * 32];   // 16 KB
    __shared__ __align__(16) bf16_t Bs[2][128 * 32];   // 16 KB

    const int tid  = threadIdx.x;
    const int lane = tid & 63;
    const int wv   = tid >> 6;   // 0..3
    const int wm   = wv >> 1;    // wave row
    const int wn   = wv & 1;     // wave col

    long ibase, jbase;
    int  jt = 0;
    if constexpr (EPI == 3) {
        // bijective XCD swizzle (4096 blocks, %8==0): XCD x owns j-panels [8x,8x+8)
        const int flat = blockIdx.y * 64 + blockIdx.x;
        const int swz  = (flat & 7) * 512 + (flat >> 3);
        ibase = (long)(swz & 63) * 128;
        jt    = swz >> 6;
        jbase = (long)jt * 128;
    } else {
        ibase = (long)blockIdx.x * 128;
        jbase = (long)blockIdx.y * 128;
    }

    // staging: per-wave-instr covers 16 rows x 32 cols (64 lanes x 16B).
    // lane -> row = l>>2, chunk = l&3; global chunk pre-swizzled: (l&3)^(row&3)
    const int srow = lane >> 2;
    const int scol = ((lane & 3) ^ (srow & 3)) << 3;  // element offset
    const long aSrc0 = (ibase + wv * 32 + srow) * (long)K + scol;
    const long bSrc0 = (jbase + wv * 32 + srow) * (long)K + scol;

    f32x4 acc[4][4] = {};
    const int fr = lane & 15;   // fragment row within 16 (C col)
    const int fj = lane >> 4;   // 16B chunk = k-octet index (C row group)
    const int crow = fj << 2;
    const int ccol = fr;

    float pf[16][4];   // pos tile, fragment layout [mr][n]
    float r0v[16];     // rn0 * C_EXP2 per fragment row
    float r1v[4];      // rn1 per fragment col
    const float* posRowBase = nullptr;
    if constexpr (EPI == 3) {
        posRowBase = pos + (size_t)(ibase + wm * 64 + crow) * NROWS + jbase + wn * 64 + ccol;
#pragma unroll
        for (int n = 0; n < 4; ++n) r1v[n] = rn1[jbase + wn * 64 + n * 16 + ccol];
#pragma unroll
        for (int mr = 0; mr < 16; ++mr)
            r0v[mr] = rn0[ibase + wm * 64 + (mr >> 2) * 16 + crow + (mr & 3)] * C_EXP2;
    }

    // ---------------- prologue: stage(0), FULL drain (safe count), barrier
#pragma unroll
    for (int s = 0; s < 2; ++s) {
        __builtin_amdgcn_global_load_lds(AS1(A + aSrc0 + s * 16 * K),
                                         AS3(&As[0][(wv * 32 + s * 16) * 32]), 16, 0, 0);
        __builtin_amdgcn_global_load_lds(AS1(B + bSrc0 + s * 16 * K),
                                         AS3(&Bs[0][(wv * 32 + s * 16) * 32]), 16, 0, 0);
    }
    asm volatile("s_waitcnt vmcnt(0)" ::: "memory");
    __builtin_amdgcn_s_barrier();
    asm volatile("" ::: "memory");

    // ---------------- pipelined K-loop (fully unrolled, compile-time t)
#pragma unroll
    for (int t = 0; t < NT; ++t) {
        if (t + 1 < NT) {
            const int nb = (t + 1) & 1;
#pragma unroll
            for (int s = 0; s < 2; ++s) {
                __builtin_amdgcn_global_load_lds(AS1(A + aSrc0 + s * 16 * K + (t + 1) * 32),
                                                 AS3(&As[nb][(wv * 32 + s * 16) * 32]), 16, 0, 0);
                __builtin_amdgcn_global_load_lds(AS1(B + bSrc0 + s * 16 * K + (t + 1) * 32),
                                                 AS3(&Bs[nb][(wv * 32 + s * 16) * 32]), 16, 0, 0);
            }
        }
        asm volatile("" ::: "memory");  // pin: pos row t issues AFTER stage(t+1)
        if constexpr (EPI == 3) {
            const float* prow = posRowBase + ((t >> 2) * 16 + (t & 3)) * (size_t)NROWS;
#pragma unroll
            for (int n = 0; n < 4; ++n)
                pf[t][n] = __builtin_nontemporal_load(prow + n * 16);
        }
        // compute on buf t&1: 4 A-frags + 4 B-frags, 16 MFMA
        {
            bf16x8 af[4], bfr[4];
#pragma unroll
            for (int m = 0; m < 4; ++m) {
                const int row = wm * 64 + m * 16 + fr;
                af[m] = *(const bf16x8*)((const char*)&As[t & 1][0] + row * 64 +
                                         ((fj ^ (fr & 3)) << 4));
            }
#pragma unroll
            for (int n = 0; n < 4; ++n) {
                const int row = wn * 64 + n * 16 + fr;
                bfr[n] = *(const bf16x8*)((const char*)&Bs[t & 1][0] + row * 64 +
                                          ((fj ^ (fr & 3)) << 4));
            }
            __builtin_amdgcn_s_setprio(1);
#pragma unroll
            for (int m = 0; m < 4; ++m)
#pragma unroll
                for (int n = 0; n < 4; ++n)
                    acc[m][n] = __builtin_amdgcn_mfma_f32_16x16x32_bf16(af[m], bfr[n],
                                                                        acc[m][n], 0, 0, 0);
            __builtin_amdgcn_s_setprio(0);
        }
        asm volatile("" ::: "memory");
        if (t + 1 < NT) {
            // counted: drains stage(t+1) (+older pos); pos row t floats across barrier
            if constexpr (EPI == 3) asm volatile("s_waitcnt vmcnt(4)" ::: "memory");
            else                    asm volatile("s_waitcnt vmcnt(0)" ::: "memory");
        }
        __builtin_amdgcn_s_barrier();
        asm volatile("" ::: "memory");
    }

    if constexpr (EPI == 1 || EPI == 2) {
#pragma unroll
        for (int m = 0; m < 4; ++m) {
            const long rowb = ibase + wm * 64 + m * 16 + crow;
#pragma unroll
            for (int n = 0; n < 4; ++n) {
                const int col = (int)jbase + wn * 64 + n * 16 + ccol;
                const float bv = bias[col];
#pragma unroll
                for (int r = 0; r < 4; ++r) {
                    float v = acc[m][n][r] + bv;
                    const long idx = (rowb + r) * HDIM + col;
                    if constexpr (EPI == 1) {
                        v = v > 0.f ? v : expm1f(v);  // ELU(alpha=1)
                        outb[idx] = (bf16_t)v;
                    } else {
                        outf[idx] = v;
                        outb[idx] = (bf16_t)v;
                    }
                }
            }
        }
    } else {
        // epilogue: exp2 + LDS reduce. Scratch [wn][128 rows][16 cols] f32
        // = 16 KB per array, exactly overlaying As / Bs (K-loop done).
        float* sS = (float*)&As[0][0];
        float* sP = (float*)&Bs[0][0];
#pragma unroll
        for (int mr = 0; mr < 16; ++mr) {
            const int row = wm * 64 + (mr >> 2) * 16 + crow + (mr & 3);  // 0..127
            float eS = 0.f, eP = 0.f;
#pragma unroll
            for (int n = 0; n < 4; ++n) {
                const float e = exp2f(acc[mr >> 2][n][mr & 3] * r0v[mr] * r1v[n]);
                eS += e;
                eP += e * pf[mr][n];
            }
            sS[(wn * 128 + row) * 16 + ccol] = eS;
            sP[(wn * 128 + row) * 16 + ccol] = eP;
        }
        __syncthreads();
        if (tid < 128) {
            const int rr = tid;
            float S = 0.f, P = 0.f;
#pragma unroll
            for (int h = 0; h < 2; ++h) {
                const float* bS = &sS[(h * 128 + rr) * 16];
                const float* bP = &sP[(h * 128 + rr) * 16];
#pragma unroll
                for (int c = 0; c < 16; c += 4) {
                    f32x4 v = *(const f32x4*)(bS + c);
                    f32x4 w = *(const f32x4*)(bP + c);
                    S += v[0] + v[1] + v[2] + v[3];
                    P += w[0] + w[1] + w[2] + w[3];
                }
            }
            pS[(long)jt * NROWS + ibase + rr] = S;
            pP[(long)jt * NROWS + ibase + rr] = P;
        }
    }
}

// ---------------------------------------------------------------- row norms
__global__ __launch_bounds__(256) void rownorm(const bf16_t* __restrict__ Z,
                                               float* __restrict__ rn) {
    const int row  = blockIdx.x * 4 + (threadIdx.x >> 6);
    const int lane = threadIdx.x & 63;
    bf16x8 v = *(const bf16x8*)&Z[(size_t)row * HDIM + lane * 8];
    float s = 0.f;
#pragma unroll
    for (int j = 0; j < 8; ++j) { float f = (float)v[j]; s += f * f; }
#pragma unroll
    for (int off = 32; off > 0; off >>= 1) s += __shfl_xor(s, off);
    if (lane == 0) rn[row] = rsqrtf(s);
}

// ---------------------------------------------------------------- reductions
__global__ __launch_bounds__(256) void reduce_rows(const float* __restrict__ pS,
                                                   const float* __restrict__ pP,
                                                   float* __restrict__ bsum) {
    const int i = blockIdx.x * 256 + threadIdx.x;  // row 0..8191
    float S = 0.f, P = 0.f;
    for (int jb = 0; jb < 64; ++jb) {
        S += pS[jb * NROWS + i];
        P += pP[jb * NROWS + i];
    }
    float t = logf(P / (S + 1e-8f) + 1e-8f);
#pragma unroll
    for (int off = 32; off > 0; off >>= 1) t += __shfl_xor(t, off);
    __shared__ float red[4];
    if ((threadIdx.x & 63) == 0) red[threadIdx.x >> 6] = t;
    __syncthreads();
    if (threadIdx.x == 0) bsum[blockIdx.x] = red[0] + red[1] + red[2] + red[3];
}

__global__ void finalize(const float* __restrict__ bsum, float* __restrict__ loss) {
    float t = (threadIdx.x < 32) ? bsum[threadIdx.x] : 0.f;
#pragma unroll
    for (int off = 32; off > 0; off >>= 1) t += __shfl_xor(t, off);
    if (threadIdx.x == 0) *loss = -(t * (1.0f / 8192.0f));
}

// ---------------------------------------------------------------- launch
extern "C" void kernel_launch(void* const* d_in, const int* in_sizes, int n_in,
                              void* d_out, int out_size, void* d_ws, size_t ws_size,
                              hipStream_t stream) {
    const float* embd0 = (const float*)d_in[0];
    const float* embd1 = (const float*)d_in[1];
    const float* pos   = (const float*)d_in[2];
    const float* W1    = (const float*)d_in[3];
    const float* b1    = (const float*)d_in[4];
    const float* W2    = (const float*)d_in[5];
    const float* b2    = (const float*)d_in[6];
    float* out = (float*)d_out;  // [z0 | z1 | loss]

    char* ws = (char*)d_ws;
    bf16_t* Xb   = (bf16_t*)(ws);               // 16 MB  [16384][512]
    bf16_t* Hb   = (bf16_t*)(ws + 16777216);    // 16 MB
    bf16_t* Zb   = (bf16_t*)(ws + 33554432);    // 16 MB
    bf16_t* W1b  = (bf16_t*)(ws + 50331648);    // 512 KB
    bf16_t* W2b  = (bf16_t*)(ws + 50855936);    // 512 KB
    float*  rn   = (float*)(ws + 51380224);     // 64 KB (rn0|rn1)
    float*  pS   = (float*)(ws + 51445760);     // 2 MB [64][8192]
    float*  pP   = (float*)(ws + 53542912);     // 2 MB
    float*  bsum = (float*)(ws + 55640064);     // 128 B

    cvt_f32_bf16<<<2048, 256, 0, stream>>>(embd0, Xb, 524288);
    cvt_f32_bf16<<<2048, 256, 0, stream>>>(embd1, Xb + 4194304, 524288);
    cvt_f32_bf16<<<128, 256, 0, stream>>>(W1, W1b, 32768);
    cvt_f32_bf16<<<128, 256, 0, stream>>>(W2, W2b, 32768);

    gemm_bt<1><<<dim3(128, 4), 256, 0, stream>>>(Xb, W1b, b1, Hb, nullptr,
                                                 nullptr, nullptr, nullptr, nullptr, nullptr);
    gemm_bt<2><<<dim3(128, 4), 256, 0, stream>>>(Hb, W2b, b2, Zb, out,
                                                 nullptr, nullptr, nullptr, nullptr, nullptr);
    rownorm<<<4096, 256, 0, stream>>>(Zb, rn);
    gemm_bt<3><<<dim3(64, 64), 256, 0, stream>>>(Zb, Zb + 4194304, nullptr,
                                                 nullptr, nullptr, rn, rn + NROWS, pos,
                                                 pS, pP);
    reduce_rows<<<32, 256, 0, stream>>>(pS, pP, bsum);
    finalize<<<1, 64, 0, stream>>>(bsum, out + 8388608);
}

// Round 6
// 276.308 us; speedup vs baseline: 1.3792x; 1.3792x over previous
//
#include <hip/hip_runtime.h>
#include <hip/hip_bf16.h>
#include <cmath>

typedef __bf16 bf16_t;
typedef __bf16 bf16x8 __attribute__((ext_vector_type(8)));
typedef float  f32x4  __attribute__((ext_vector_type(4)));

#define AS1(p) ((__attribute__((address_space(1))) void*)(p))
#define AS3(p) ((__attribute__((address_space(3))) void*)(p))

// N=8192, H=512, TAU=0.5, EPS=1e-8
// exp(x) = exp2(x * log2e / TAU); (1/0.5)*log2e = 2.885390...
#define C_EXP2 2.8853900817779268f
#define NROWS  8192
#define HDIM   512

// ---------------------------------------------------------------- f32->bf16
__global__ __launch_bounds__(256) void cvt_f32_bf16(const float* __restrict__ src,
                                                    bf16_t* __restrict__ dst, int n8) {
    int i = blockIdx.x * 256 + threadIdx.x;
    if (i >= n8) return;
    const f32x4* s4 = (const f32x4*)src;
    f32x4 a = s4[2 * (size_t)i];
    f32x4 b = s4[2 * (size_t)i + 1];
    bf16x8 o;
#pragma unroll
    for (int j = 0; j < 4; ++j) { o[j] = (bf16_t)a[j]; o[4 + j] = (bf16_t)b[j]; }
    *(bf16x8*)(dst + 8 * (size_t)i) = o;
}

// ---------------------------------------------------------------- GEMM (NT)
// C[i][j] = sum_k A[i*K+k] * B[j*K+k], K=512. 128x128 tile, BK=64, NT=8,
// 2-deep dbuf (64 KB LDS, 2 blocks/CU), fully-unrolled pipeline,
// raw s_barrier + vmcnt(0)/step; at t==6 (EPI3): issue the WHOLE 64 KB pos
// tile as 16 coalesced dwordx4/thread behind stage(7), vmcnt(16) keeps them
// in flight across the last steps + e-write phase.
// LDS XOR swizzle (16B chunks, chunk ^= row&7): ds_read_b128 2-way (free).
// EPI=1: bias+ELU -> bf16   EPI=2: bias -> f32 (d_out) + bf16 copy
// EPI=3: e=exp2(acc*rn0*rn1*C) -> LDS e[128][128]; reader threads (1 per
//        row-half) sum e and e*pos (pos from prefetched regs) -> pS/pP
template <int EPI>
__global__ __launch_bounds__(256, 2)
void gemm_bt(const bf16_t* __restrict__ A, const bf16_t* __restrict__ B,
             const float* __restrict__ bias,
             bf16_t* __restrict__ outb, float* __restrict__ outf,
             const float* __restrict__ rn0, const float* __restrict__ rn1,
             const float* __restrict__ pos,
             float* __restrict__ pS, float* __restrict__ pP) {
    constexpr int K  = 512;
    constexpr int NT = 8;
    // As dbuf: [0,32K) ; Bs dbuf: [32K,64K) ; epilogue e[128][128] f32: all 64K
    __shared__ __align__(16) char smem[65536];

    const int tid  = threadIdx.x;
    const int lane = tid & 63;
    const int wv   = tid >> 6;   // 0..3
    const int wm   = wv >> 1;    // wave row
    const int wn   = wv & 1;     // wave col

    long ibase, jbase;
    int  jt = 0;
    if constexpr (EPI == 3) {
        // bijective XCD swizzle (4096 blocks, %8==0): XCD x owns j-panels [8x,8x+8)
        const int flat = blockIdx.y * 64 + blockIdx.x;
        const int swz  = (flat & 7) * 512 + (flat >> 3);
        ibase = (long)(swz & 63) * 128;
        jt    = swz >> 6;
        jbase = (long)jt * 128;
    } else {
        ibase = (long)blockIdx.x * 128;
        jbase = (long)blockIdx.y * 128;
    }

    const int r8  = lane >> 3;   // row within 8-row staging chunk
    const int c16 = lane & 7;    // 16B chunk within 128B row
    const long aSrc0 = (ibase + wv * 32 + r8) * (long)K + ((c16 ^ r8) << 3);
    const long bSrc0 = (jbase + wv * 32 + r8) * (long)K + ((c16 ^ r8) << 3);

    f32x4 acc[4][4] = {};
    const int fr = lane & 15;   // fragment row within 16 (C col)
    const int fj = lane >> 4;   // 16B chunk index (C row group)
    const int crow = fj << 2;
    const int ccol = fr;

    float r0v[16];     // rn0 * C_EXP2 per fragment row
    float r1v[4];      // rn1 per fragment col
    if constexpr (EPI == 3) {
#pragma unroll
        for (int n = 0; n < 4; ++n) r1v[n] = rn1[jbase + wn * 64 + n * 16 + ccol];
#pragma unroll
        for (int mr = 0; mr < 16; ++mr)
            r0v[mr] = rn0[ibase + wm * 64 + (mr >> 2) * 16 + crow + (mr & 3)] * C_EXP2;
    }
    f32x4 pv[16];                      // pos row-half, 16B/lane coalesced
    const int erow  = tid >> 1;        // epilogue row 0..127
    const int ehalf = tid & 1;         // col half

    // ---------------- prologue: stage(0), full drain, barrier
#pragma unroll
    for (int s = 0; s < 4; ++s) {
        const int ro = (wv * 32 + s * 8) * 128;
        __builtin_amdgcn_global_load_lds(AS1(A + aSrc0 + s * 8 * K),
                                         AS3(smem + ro), 16, 0, 0);
        __builtin_amdgcn_global_load_lds(AS1(B + bSrc0 + s * 8 * K),
                                         AS3(smem + 32768 + ro), 16, 0, 0);
    }
    asm volatile("s_waitcnt vmcnt(0)" ::: "memory");
    __builtin_amdgcn_s_barrier();
    asm volatile("" ::: "memory");

    // ---------------- pipelined K-loop (fully unrolled, compile-time t)
#pragma unroll
    for (int t = 0; t < NT; ++t) {
        if (t + 1 < NT) {
            const int nb = (t + 1) & 1;
#pragma unroll
            for (int s = 0; s < 4; ++s) {
                const int ro = (wv * 32 + s * 8) * 128;
                __builtin_amdgcn_global_load_lds(AS1(A + aSrc0 + s * 8 * K + (t + 1) * 64),
                                                 AS3(smem + nb * 16384 + ro), 16, 0, 0);
                __builtin_amdgcn_global_load_lds(AS1(B + bSrc0 + s * 8 * K + (t + 1) * 64),
                                                 AS3(smem + 32768 + nb * 16384 + ro), 16, 0, 0);
            }
        }
        asm volatile("" ::: "memory");  // pin: pos burst issues AFTER stage(7)
        if constexpr (EPI == 3) {
            if (t == 6) {
                const float* pbase = pos + (size_t)(ibase + erow) * NROWS + jbase + ehalf * 64;
#pragma unroll
                for (int j = 0; j < 16; ++j)
                    pv[j] = __builtin_nontemporal_load((const f32x4*)(pbase + j * 4));
            }
        }
        // compute on buf t&1: 2 k-halves x 16 MFMA
#pragma unroll
        for (int kk = 0; kk < 2; ++kk) {
            bf16x8 af[4], bfr[4];
#pragma unroll
            for (int m = 0; m < 4; ++m) {
                const int row = wm * 64 + m * 16 + fr;
                af[m] = *(const bf16x8*)(smem + (t & 1) * 16384 + row * 128 +
                                         (((kk * 4 + fj) ^ (fr & 7)) << 4));
            }
#pragma unroll
            for (int n = 0; n < 4; ++n) {
                const int row = wn * 64 + n * 16 + fr;
                bfr[n] = *(const bf16x8*)(smem + 32768 + (t & 1) * 16384 + row * 128 +
                                          (((kk * 4 + fj) ^ (fr & 7)) << 4));
            }
            __builtin_amdgcn_s_setprio(1);
#pragma unroll
            for (int m = 0; m < 4; ++m)
#pragma unroll
                for (int n = 0; n < 4; ++n)
                    acc[m][n] = __builtin_amdgcn_mfma_f32_16x16x32_bf16(af[m], bfr[n],
                                                                        acc[m][n], 0, 0, 0);
            __builtin_amdgcn_s_setprio(0);
        }
        asm volatile("" ::: "memory");
        if (t + 1 < NT) {
            // t==6 (EPI3): drain stage(7) only; the 16 pos loads (younger) float
            if (EPI == 3 && t == 6) asm volatile("s_waitcnt vmcnt(16)" ::: "memory");
            else                    asm volatile("s_waitcnt vmcnt(0)" ::: "memory");
        }
        __builtin_amdgcn_s_barrier();
        asm volatile("" ::: "memory");
    }

    if constexpr (EPI == 1 || EPI == 2) {
#pragma unroll
        for (int m = 0; m < 4; ++m) {
            const long rowb = ibase + wm * 64 + m * 16 + crow;
#pragma unroll
            for (int n = 0; n < 4; ++n) {
                const int col = (int)jbase + wn * 64 + n * 16 + ccol;
                const float bv = bias[col];
#pragma unroll
                for (int r = 0; r < 4; ++r) {
                    float v = acc[m][n][r] + bv;
                    const long idx = (rowb + r) * HDIM + col;
                    if constexpr (EPI == 1) {
                        v = v > 0.f ? v : expm1f(v);  // ELU(alpha=1)
                        outb[idx] = (bf16_t)v;
                    } else {
                        outf[idx] = v;
                        outb[idx] = (bf16_t)v;
                    }
                }
            }
        }
    } else {
        // ---- e-materialization: e[row][col] f32 over the dead 64 KB LDS.
        // Swizzle: 16B chunk index (col>>2) ^= row&7 -> 2-way write, <=8-way read.
        float* eB = (float*)smem;
#pragma unroll
        for (int mr = 0; mr < 16; ++mr) {
            const int m = mr >> 2, r = mr & 3;
            const int row = wm * 64 + m * 16 + crow + r;   // 0..127
#pragma unroll
            for (int n = 0; n < 4; ++n) {
                const int col = wn * 64 + n * 16 + ccol;   // 0..127
                const float e = exp2f(acc[m][n][r] * r0v[mr] * r1v[n]);
                eB[row * 128 + ((((col >> 2) ^ (row & 7)) << 2) | (col & 3))] = e;
            }
        }
        __syncthreads();
        // ---- reader: thread owns (row, col-half); pos already in pv regs
        float S = 0.f, P = 0.f;
#pragma unroll
        for (int j = 0; j < 16; ++j) {
            const int slot = (ehalf * 16 + j) ^ (erow & 7);
            const f32x4 e4 = *(const f32x4*)&eB[erow * 128 + slot * 4];
            S += e4[0] + e4[1] + e4[2] + e4[3];
            P += e4[0] * pv[j][0] + e4[1] * pv[j][1] + e4[2] * pv[j][2] + e4[3] * pv[j][3];
        }
        S += __shfl_xor(S, 1);   // combine the two col-halves (adjacent lanes)
        P += __shfl_xor(P, 1);
        if (ehalf == 0) {
            pS[(long)jt * NROWS + ibase + erow] = S;
            pP[(long)jt * NROWS + ibase + erow] = P;
        }
    }
}

// ---------------------------------------------------------------- row norms
__global__ __launch_bounds__(256) void rownorm(const bf16_t* __restrict__ Z,
                                               float* __restrict__ rn) {
    const int row  = blockIdx.x * 4 + (threadIdx.x >> 6);
    const int lane = threadIdx.x & 63;
    bf16x8 v = *(const bf16x8*)&Z[(size_t)row * HDIM + lane * 8];
    float s = 0.f;
#pragma unroll
    for (int j = 0; j < 8; ++j) { float f = (float)v[j]; s += f * f; }
#pragma unroll
    for (int off = 32; off > 0; off >>= 1) s += __shfl_xor(s, off);
    if (lane == 0) rn[row] = rsqrtf(s);
}

// ---------------------------------------------------------------- reductions
__global__ __launch_bounds__(256) void reduce_rows(const float* __restrict__ pS,
                                                   const float* __restrict__ pP,
                                                   float* __restrict__ bsum) {
    const int i = blockIdx.x * 256 + threadIdx.x;  // row 0..8191
    float S = 0.f, P = 0.f;
    for (int jb = 0; jb < 64; ++jb) {
        S += pS[jb * NROWS + i];
        P += pP[jb * NROWS + i];
    }
    float t = logf(P / (S + 1e-8f) + 1e-8f);
#pragma unroll
    for (int off = 32; off > 0; off >>= 1) t += __shfl_xor(t, off);
    __shared__ float red[4];
    if ((threadIdx.x & 63) == 0) red[threadIdx.x >> 6] = t;
    __syncthreads();
    if (threadIdx.x == 0) bsum[blockIdx.x] = red[0] + red[1] + red[2] + red[3];
}

__global__ void finalize(const float* __restrict__ bsum, float* __restrict__ loss) {
    float t = (threadIdx.x < 32) ? bsum[threadIdx.x] : 0.f;
#pragma unroll
    for (int off = 32; off > 0; off >>= 1) t += __shfl_xor(t, off);
    if (threadIdx.x == 0) *loss = -(t * (1.0f / 8192.0f));
}

// ---------------------------------------------------------------- launch
extern "C" void kernel_launch(void* const* d_in, const int* in_sizes, int n_in,
                              void* d_out, int out_size, void* d_ws, size_t ws_size,
                              hipStream_t stream) {
    const float* embd0 = (const float*)d_in[0];
    const float* embd1 = (const float*)d_in[1];
    const float* pos   = (const float*)d_in[2];
    const float* W1    = (const float*)d_in[3];
    const float* b1    = (const float*)d_in[4];
    const float* W2    = (const float*)d_in[5];
    const float* b2    = (const float*)d_in[6];
    float* out = (float*)d_out;  // [z0 | z1 | loss]

    char* ws = (char*)d_ws;
    bf16_t* Xb   = (bf16_t*)(ws);               // 16 MB  [16384][512]
    bf16_t* Hb   = (bf16_t*)(ws + 16777216);    // 16 MB
    bf16_t* Zb   = (bf16_t*)(ws + 33554432);    // 16 MB
    bf16_t* W1b  = (bf16_t*)(ws + 50331648);    // 512 KB
    bf16_t* W2b  = (bf16_t*)(ws + 50855936);    // 512 KB
    float*  rn   = (float*)(ws + 51380224);     // 64 KB (rn0|rn1)
    float*  pS   = (float*)(ws + 51445760);     // 2 MB [64][8192]
    float*  pP   = (float*)(ws + 53542912);     // 2 MB
    float*  bsum = (float*)(ws + 55640064);     // 128 B

    cvt_f32_bf16<<<2048, 256, 0, stream>>>(embd0, Xb, 524288);
    cvt_f32_bf16<<<2048, 256, 0, stream>>>(embd1, Xb + 4194304, 524288);
    cvt_f32_bf16<<<128, 256, 0, stream>>>(W1, W1b, 32768);
    cvt_f32_bf16<<<128, 256, 0, stream>>>(W2, W2b, 32768);

    gemm_bt<1><<<dim3(128, 4), 256, 0, stream>>>(Xb, W1b, b1, Hb, nullptr,
                                                 nullptr, nullptr, nullptr, nullptr, nullptr);
    gemm_bt<2><<<dim3(128, 4), 256, 0, stream>>>(Hb, W2b, b2, Zb, out,
                                                 nullptr, nullptr, nullptr, nullptr, nullptr);
    rownorm<<<4096, 256, 0, stream>>>(Zb, rn);
    gemm_bt<3><<<dim3(64, 64), 256, 0, stream>>>(Zb, Zb + 4194304, nullptr,
                                                 nullptr, nullptr, rn, rn + NROWS, pos,
                                                 pS, pP);
    reduce_rows<<<32, 256, 0, stream>>>(pS, pP, bsum);
    finalize<<<1, 64, 0, stream>>>(bsum, out + 8388608);
}

// Round 7
// 275.280 us; speedup vs baseline: 1.3843x; 1.0037x over previous
//
#include <hip/hip_runtime.h>
#include <hip/hip_bf16.h>
#include <cmath>

typedef __bf16 bf16_t;
typedef __bf16 bf16x8 __attribute__((ext_vector_type(8)));
typedef float  f32x4  __attribute__((ext_vector_type(4)));

#define AS1(p) ((__attribute__((address_space(1))) void*)(p))
#define AS3(p) ((__attribute__((address_space(3))) void*)(p))

// N=8192, H=512, TAU=0.5, EPS=1e-8
// exp(x) = exp2(x * log2e / TAU); (1/0.5)*log2e = 2.885390...
#define C_EXP2 2.8853900817779268f
#define NROWS  8192
#define HDIM   512

// ---------------------------------------------------------------- f32->bf16
__global__ __launch_bounds__(256) void cvt_f32_bf16(const float* __restrict__ src,
                                                    bf16_t* __restrict__ dst, int n8) {
    int i = blockIdx.x * 256 + threadIdx.x;
    if (i >= n8) return;
    const f32x4* s4 = (const f32x4*)src;
    f32x4 a = s4[2 * (size_t)i];
    f32x4 b = s4[2 * (size_t)i + 1];
    bf16x8 o;
#pragma unroll
    for (int j = 0; j < 4; ++j) { o[j] = (bf16_t)a[j]; o[4 + j] = (bf16_t)b[j]; }
    *(bf16x8*)(dst + 8 * (size_t)i) = o;
}

// ---------------------------------------------------------------- GEMM (NT)
// C[i][j] = sum_k A[i*K+k] * B[j*K+k], K=512. 128x128 tile, BK=64, NT=8,
// 2-deep dbuf (64 KB LDS, 2 blocks/CU), fully-unrolled pipeline,
// raw s_barrier + counted vmcnt.
// EPI3 pos plumbing (R4 cadence, widened): per step t issue S(t+1) [8 instr]
// then pos chunks 2t,2t+1 [2 x dwordx4/thread, coalesced full lines];
// end-of-step vmcnt(2): drains S(t+1) (aged 1 step) + pos(t-1) (aged 2
// steps), leaves pos(t) in flight across the barrier. No nontemporal.
// LDS XOR swizzle (16B chunks, chunk ^= row&7): ds_read_b128 2-way (free).
// EPI=1: bias+ELU -> bf16   EPI=2: bias -> f32 (d_out) + bf16 copy
// EPI=3: e=exp2(acc*rn0*rn1*C) -> LDS e[128][128]; reader threads (1 per
//        row-half) sum e and e*pos (pos from pv regs) -> pS/pP
template <int EPI>
__global__ __launch_bounds__(256, 2)
void gemm_bt(const bf16_t* __restrict__ A, const bf16_t* __restrict__ B,
             const float* __restrict__ bias,
             bf16_t* __restrict__ outb, float* __restrict__ outf,
             const float* __restrict__ rn0, const float* __restrict__ rn1,
             const float* __restrict__ pos,
             float* __restrict__ pS, float* __restrict__ pP) {
    constexpr int K  = 512;
    constexpr int NT = 8;
    // As dbuf: [0,32K) ; Bs dbuf: [32K,64K) ; epilogue e[128][128] f32: all 64K
    __shared__ __align__(16) char smem[65536];

    const int tid  = threadIdx.x;
    const int lane = tid & 63;
    const int wv   = tid >> 6;   // 0..3
    const int wm   = wv >> 1;    // wave row
    const int wn   = wv & 1;     // wave col

    long ibase, jbase;
    int  jt = 0;
    if constexpr (EPI == 3) {
        // bijective XCD swizzle (4096 blocks, %8==0): XCD x owns j-panels [8x,8x+8)
        const int flat = blockIdx.y * 64 + blockIdx.x;
        const int swz  = (flat & 7) * 512 + (flat >> 3);
        ibase = (long)(swz & 63) * 128;
        jt    = swz >> 6;
        jbase = (long)jt * 128;
    } else {
        ibase = (long)blockIdx.x * 128;
        jbase = (long)blockIdx.y * 128;
    }

    const int r8  = lane >> 3;   // row within 8-row staging chunk
    const int c16 = lane & 7;    // 16B chunk within 128B row
    const long aSrc0 = (ibase + wv * 32 + r8) * (long)K + ((c16 ^ r8) << 3);
    const long bSrc0 = (jbase + wv * 32 + r8) * (long)K + ((c16 ^ r8) << 3);

    f32x4 acc[4][4] = {};
    const int fr = lane & 15;   // fragment row within 16 (C col)
    const int fj = lane >> 4;   // 16B chunk index (C row group)
    const int crow = fj << 2;
    const int ccol = fr;

    float r0v[16];     // rn0 * C_EXP2 per fragment row
    float r1v[4];      // rn1 per fragment col
    if constexpr (EPI == 3) {
#pragma unroll
        for (int n = 0; n < 4; ++n) r1v[n] = rn1[jbase + wn * 64 + n * 16 + ccol];
#pragma unroll
        for (int mr = 0; mr < 16; ++mr)
            r0v[mr] = rn0[ibase + wm * 64 + (mr >> 2) * 16 + crow + (mr & 3)] * C_EXP2;
    }
    f32x4 pv[16];                      // pos row-half: 16 x 16B chunks
    const int erow  = tid >> 1;        // epilogue row 0..127
    const int ehalf = tid & 1;         // col half (64 floats)
    const float* pbase = nullptr;
    if constexpr (EPI == 3)
        pbase = pos + (size_t)(ibase + erow) * NROWS + jbase + ehalf * 64;

    // ---------------- prologue: stage(0), full drain, barrier
#pragma unroll
    for (int s = 0; s < 4; ++s) {
        const int ro = (wv * 32 + s * 8) * 128;
        __builtin_amdgcn_global_load_lds(AS1(A + aSrc0 + s * 8 * K),
                                         AS3(smem + ro), 16, 0, 0);
        __builtin_amdgcn_global_load_lds(AS1(B + bSrc0 + s * 8 * K),
                                         AS3(smem + 32768 + ro), 16, 0, 0);
    }
    asm volatile("s_waitcnt vmcnt(0)" ::: "memory");
    __builtin_amdgcn_s_barrier();
    asm volatile("" ::: "memory");

    // ---------------- pipelined K-loop (fully unrolled, compile-time t)
#pragma unroll
    for (int t = 0; t < NT; ++t) {
        if (t + 1 < NT) {
            const int nb = (t + 1) & 1;
#pragma unroll
            for (int s = 0; s < 4; ++s) {
                const int ro = (wv * 32 + s * 8) * 128;
                __builtin_amdgcn_global_load_lds(AS1(A + aSrc0 + s * 8 * K + (t + 1) * 64),
                                                 AS3(smem + nb * 16384 + ro), 16, 0, 0);
                __builtin_amdgcn_global_load_lds(AS1(B + bSrc0 + s * 8 * K + (t + 1) * 64),
                                                 AS3(smem + 32768 + nb * 16384 + ro), 16, 0, 0);
            }
        }
        asm volatile("" ::: "memory");  // pin: pos chunks issue AFTER stage(t+1)
        if constexpr (EPI == 3) {
            pv[2 * t]     = *(const f32x4*)(pbase + (2 * t) * 4);
            pv[2 * t + 1] = *(const f32x4*)(pbase + (2 * t + 1) * 4);
        }
        // compute on buf t&1: 2 k-halves x 16 MFMA
#pragma unroll
        for (int kk = 0; kk < 2; ++kk) {
            bf16x8 af[4], bfr[4];
#pragma unroll
            for (int m = 0; m < 4; ++m) {
                const int row = wm * 64 + m * 16 + fr;
                af[m] = *(const bf16x8*)(smem + (t & 1) * 16384 + row * 128 +
                                         (((kk * 4 + fj) ^ (fr & 7)) << 4));
            }
#pragma unroll
            for (int n = 0; n < 4; ++n) {
                const int row = wn * 64 + n * 16 + fr;
                bfr[n] = *(const bf16x8*)(smem + 32768 + (t & 1) * 16384 + row * 128 +
                                          (((kk * 4 + fj) ^ (fr & 7)) << 4));
            }
            __builtin_amdgcn_s_setprio(1);
#pragma unroll
            for (int m = 0; m < 4; ++m)
#pragma unroll
                for (int n = 0; n < 4; ++n)
                    acc[m][n] = __builtin_amdgcn_mfma_f32_16x16x32_bf16(af[m], bfr[n],
                                                                        acc[m][n], 0, 0, 0);
            __builtin_amdgcn_s_setprio(0);
        }
        asm volatile("" ::: "memory");
        if (t + 1 < NT) {
            // EPI3 ledger: [pos(t-1):2][S(t+1):8][pos(t):2] -> vmcnt(2)
            // drains S(t+1) (1-step aged) + pos(t-1) (2-step aged); pos(t) floats.
            if constexpr (EPI == 3) asm volatile("s_waitcnt vmcnt(2)" ::: "memory");
            else                    asm volatile("s_waitcnt vmcnt(0)" ::: "memory");
        }
        __builtin_amdgcn_s_barrier();
        asm volatile("" ::: "memory");
    }

    if constexpr (EPI == 1 || EPI == 2) {
#pragma unroll
        for (int m = 0; m < 4; ++m) {
            const long rowb = ibase + wm * 64 + m * 16 + crow;
#pragma unroll
            for (int n = 0; n < 4; ++n) {
                const int col = (int)jbase + wn * 64 + n * 16 + ccol;
                const float bv = bias[col];
#pragma unroll
                for (int r = 0; r < 4; ++r) {
                    float v = acc[m][n][r] + bv;
                    const long idx = (rowb + r) * HDIM + col;
                    if constexpr (EPI == 1) {
                        v = v > 0.f ? v : expm1f(v);  // ELU(alpha=1)
                        outb[idx] = (bf16_t)v;
                    } else {
                        outf[idx] = v;
                        outb[idx] = (bf16_t)v;
                    }
                }
            }
        }
    } else {
        // ---- e-materialization: e[row][col] f32 over the dead 64 KB LDS.
        // Swizzle: 16B chunk index (col>>2) ^= row&7 -> 2-way write, <=8-way read.
        float* eB = (float*)smem;
#pragma unroll
        for (int mr = 0; mr < 16; ++mr) {
            const int m = mr >> 2, r = mr & 3;
            const int row = wm * 64 + m * 16 + crow + r;   // 0..127
#pragma unroll
            for (int n = 0; n < 4; ++n) {
                const int col = wn * 64 + n * 16 + ccol;   // 0..127
                const float e = exp2f(acc[m][n][r] * r0v[mr] * r1v[n]);
                eB[row * 128 + ((((col >> 2) ^ (row & 7)) << 2) | (col & 3))] = e;
            }
        }
        __syncthreads();
        // ---- reader: thread owns (row, col-half); pos already in pv regs
        float S = 0.f, P = 0.f;
#pragma unroll
        for (int j = 0; j < 16; ++j) {
            const int slot = (ehalf * 16 + j) ^ (erow & 7);
            const f32x4 e4 = *(const f32x4*)&eB[erow * 128 + slot * 4];
            S += e4[0] + e4[1] + e4[2] + e4[3];
            P += e4[0] * pv[j][0] + e4[1] * pv[j][1] + e4[2] * pv[j][2] + e4[3] * pv[j][3];
        }
        S += __shfl_xor(S, 1);   // combine the two col-halves (adjacent lanes)
        P += __shfl_xor(P, 1);
        if (ehalf == 0) {
            pS[(long)jt * NROWS + ibase + erow] = S;
            pP[(long)jt * NROWS + ibase + erow] = P;
        }
    }
}

// ---------------------------------------------------------------- row norms
__global__ __launch_bounds__(256) void rownorm(const bf16_t* __restrict__ Z,
                                               float* __restrict__ rn) {
    const int row  = blockIdx.x * 4 + (threadIdx.x >> 6);
    const int lane = threadIdx.x & 63;
    bf16x8 v = *(const bf16x8*)&Z[(size_t)row * HDIM + lane * 8];
    float s = 0.f;
#pragma unroll
    for (int j = 0; j < 8; ++j) { float f = (float)v[j]; s += f * f; }
#pragma unroll
    for (int off = 32; off > 0; off >>= 1) s += __shfl_xor(s, off);
    if (lane == 0) rn[row] = rsqrtf(s);
}

// ---------------------------------------------------------------- reductions
__global__ __launch_bounds__(256) void reduce_rows(const float* __restrict__ pS,
                                                   const float* __restrict__ pP,
                                                   float* __restrict__ bsum) {
    const int i = blockIdx.x * 256 + threadIdx.x;  // row 0..8191
    float S = 0.f, P = 0.f;
    for (int jb = 0; jb < 64; ++jb) {
        S += pS[jb * NROWS + i];
        P += pP[jb * NROWS + i];
    }
    float t = logf(P / (S + 1e-8f) + 1e-8f);
#pragma unroll
    for (int off = 32; off > 0; off >>= 1) t += __shfl_xor(t, off);
    __shared__ float red[4];
    if ((threadIdx.x & 63) == 0) red[threadIdx.x >> 6] = t;
    __syncthreads();
    if (threadIdx.x == 0) bsum[blockIdx.x] = red[0] + red[1] + red[2] + red[3];
}

__global__ void finalize(const float* __restrict__ bsum, float* __restrict__ loss) {
    float t = (threadIdx.x < 32) ? bsum[threadIdx.x] : 0.f;
#pragma unroll
    for (int off = 32; off > 0; off >>= 1) t += __shfl_xor(t, off);
    if (threadIdx.x == 0) *loss = -(t * (1.0f / 8192.0f));
}

// ---------------------------------------------------------------- launch
extern "C" void kernel_launch(void* const* d_in, const int* in_sizes, int n_in,
                              void* d_out, int out_size, void* d_ws, size_t ws_size,
                              hipStream_t stream) {
    const float* embd0 = (const float*)d_in[0];
    const float* embd1 = (const float*)d_in[1];
    const float* pos   = (const float*)d_in[2];
    const float* W1    = (const float*)d_in[3];
    const float* b1    = (const float*)d_in[4];
    const float* W2    = (const float*)d_in[5];
    const float* b2    = (const float*)d_in[6];
    float* out = (float*)d_out;  // [z0 | z1 | loss]

    char* ws = (char*)d_ws;
    bf16_t* Xb   = (bf16_t*)(ws);               // 16 MB  [16384][512]
    bf16_t* Hb   = (bf16_t*)(ws + 16777216);    // 16 MB
    bf16_t* Zb   = (bf16_t*)(ws + 33554432);    // 16 MB
    bf16_t* W1b  = (bf16_t*)(ws + 50331648);    // 512 KB
    bf16_t* W2b  = (bf16_t*)(ws + 50855936);    // 512 KB
    float*  rn   = (float*)(ws + 51380224);     // 64 KB (rn0|rn1)
    float*  pS   = (float*)(ws + 51445760);     // 2 MB [64][8192]
    float*  pP   = (float*)(ws + 53542912);     // 2 MB
    float*  bsum = (float*)(ws + 55640064);     // 128 B

    cvt_f32_bf16<<<2048, 256, 0, stream>>>(embd0, Xb, 524288);
    cvt_f32_bf16<<<2048, 256, 0, stream>>>(embd1, Xb + 4194304, 524288);
    cvt_f32_bf16<<<128, 256, 0, stream>>>(W1, W1b, 32768);
    cvt_f32_bf16<<<128, 256, 0, stream>>>(W2, W2b, 32768);

    gemm_bt<1><<<dim3(128, 4), 256, 0, stream>>>(Xb, W1b, b1, Hb, nullptr,
                                                 nullptr, nullptr, nullptr, nullptr, nullptr);
    gemm_bt<2><<<dim3(128, 4), 256, 0, stream>>>(Hb, W2b, b2, Zb, out,
                                                 nullptr, nullptr, nullptr, nullptr, nullptr);
    rownorm<<<4096, 256, 0, stream>>>(Zb, rn);
    gemm_bt<3><<<dim3(64, 64), 256, 0, stream>>>(Zb, Zb + 4194304, nullptr,
                                                 nullptr, nullptr, rn, rn + NROWS, pos,
                                                 pS, pP);
    reduce_rows<<<32, 256, 0, stream>>>(pS, pP, bsum);
    finalize<<<1, 64, 0, stream>>>(bsum, out + 8388608);
}

// Round 8
// 195.199 us; speedup vs baseline: 1.9522x; 1.4103x over previous
//
#include <hip/hip_runtime.h>
#include <hip/hip_bf16.h>
#include <cmath>

typedef __bf16 bf16_t;
typedef __bf16 bf16x8 __attribute__((ext_vector_type(8)));
typedef float  f32x4  __attribute__((ext_vector_type(4)));

#define AS1(p) ((__attribute__((address_space(1))) void*)(p))
#define AS3(p) ((__attribute__((address_space(3))) void*)(p))

// N=8192, H=512, TAU=0.5, EPS=1e-8
// exp(x) = exp2(x * log2e / TAU); (1/0.5)*log2e = 2.885390...
#define C_EXP2 2.8853900817779268f
#define NROWS  8192
#define HDIM   512

// ---------------------------------------------------------------- f32->bf16
__global__ __launch_bounds__(256) void cvt_f32_bf16(const float* __restrict__ src,
                                                    bf16_t* __restrict__ dst, int n8) {
    int i = blockIdx.x * 256 + threadIdx.x;
    if (i >= n8) return;
    const f32x4* s4 = (const f32x4*)src;
    f32x4 a = s4[2 * (size_t)i];
    f32x4 b = s4[2 * (size_t)i + 1];
    bf16x8 o;
#pragma unroll
    for (int j = 0; j < 4; ++j) { o[j] = (bf16_t)a[j]; o[4 + j] = (bf16_t)b[j]; }
    *(bf16x8*)(dst + 8 * (size_t)i) = o;
}

// ---------------------------------------------------------------- GEMM (NT)
// C[i][j] = sum_k A[i*K+k] * B[j*K+k], K=512. 128x128 tile, BK=64, NT=8,
// 2-deep dbuf (64 KB LDS, 2 blocks/CU), fully-unrolled pipeline,
// raw s_barrier + counted vmcnt.
// EPI3 pos plumbing: per step t issue S(t+1) [8 instr] then pos chunks
// i=2t,2t+1. Ownership: chunk i of thread -> row (tid>>3)+32*(i&3),
// col-chunk (tid&7)+8*(i>>2): 8 consecutive lanes read 128B contiguous of
// ONE row -> every HBM granule fully used, touched exactly once.
// vmcnt(2)/step: drains S(t+1) (1-step aged) + pos(t-1); pos(t) floats.
// LDS XOR swizzle (16B chunks, chunk ^= row&7): ds_read_b128 2-way (free).
// EPI=1: bias+ELU -> bf16   EPI=2: bias -> f32 (d_out) + bf16 copy
// EPI=3: e=exp2(acc*rn0*rn1*C) -> LDS e[128][128] (barrier-protected);
//        readers sum e, e*pos from pv regs; 8-lane shfl reduce -> pS/pP
template <int EPI>
__global__ __launch_bounds__(256, 2)
void gemm_bt(const bf16_t* __restrict__ A, const bf16_t* __restrict__ B,
             const float* __restrict__ bias,
             bf16_t* __restrict__ outb, float* __restrict__ outf,
             const float* __restrict__ rn0, const float* __restrict__ rn1,
             const float* __restrict__ pos,
             float* __restrict__ pS, float* __restrict__ pP) {
    constexpr int K  = 512;
    constexpr int NT = 8;
    // As dbuf: [0,32K) ; Bs dbuf: [32K,64K) ; epilogue e[128][128] f32: all 64K
    __shared__ __align__(16) char smem[65536];

    const int tid  = threadIdx.x;
    const int lane = tid & 63;
    const int wv   = tid >> 6;   // 0..3
    const int wm   = wv >> 1;    // wave row
    const int wn   = wv & 1;     // wave col

    long ibase, jbase;
    int  jt = 0;
    if constexpr (EPI == 3) {
        // bijective XCD swizzle (4096 blocks, %8==0): XCD x owns j-panels [8x,8x+8)
        const int flat = blockIdx.y * 64 + blockIdx.x;
        const int swz  = (flat & 7) * 512 + (flat >> 3);
        ibase = (long)(swz & 63) * 128;
        jt    = swz >> 6;
        jbase = (long)jt * 128;
    } else {
        ibase = (long)blockIdx.x * 128;
        jbase = (long)blockIdx.y * 128;
    }

    const int r8  = lane >> 3;   // row within 8-row staging chunk
    const int c16 = lane & 7;    // 16B chunk within 128B row
    const long aSrc0 = (ibase + wv * 32 + r8) * (long)K + ((c16 ^ r8) << 3);
    const long bSrc0 = (jbase + wv * 32 + r8) * (long)K + ((c16 ^ r8) << 3);

    f32x4 acc[4][4] = {};
    const int fr = lane & 15;   // fragment row within 16 (C col)
    const int fj = lane >> 4;   // 16B chunk index (C row group)
    const int crow = fj << 2;
    const int ccol = fr;

    float r0v[16];     // rn0 * C_EXP2 per fragment row
    float r1v[4];      // rn1 per fragment col
    if constexpr (EPI == 3) {
#pragma unroll
        for (int n = 0; n < 4; ++n) r1v[n] = rn1[jbase + wn * 64 + n * 16 + ccol];
#pragma unroll
        for (int mr = 0; mr < 16; ++mr)
            r0v[mr] = rn0[ibase + wm * 64 + (mr >> 2) * 16 + crow + (mr & 3)] * C_EXP2;
    }
    // pos ownership: chunk i -> row (tid>>3)+32*(i&3), col-chunk (tid&7)+8*(i>>2)
    f32x4 pv[16];
    const float* p00 = nullptr;
    if constexpr (EPI == 3)
        p00 = pos + (size_t)(ibase + (tid >> 3)) * NROWS + jbase + ((tid & 7) << 2);

    // ---------------- prologue: stage(0), full drain, barrier
#pragma unroll
    for (int s = 0; s < 4; ++s) {
        const int ro = (wv * 32 + s * 8) * 128;
        __builtin_amdgcn_global_load_lds(AS1(A + aSrc0 + s * 8 * K),
                                         AS3(smem + ro), 16, 0, 0);
        __builtin_amdgcn_global_load_lds(AS1(B + bSrc0 + s * 8 * K),
                                         AS3(smem + 32768 + ro), 16, 0, 0);
    }
    asm volatile("s_waitcnt vmcnt(0)" ::: "memory");
    __builtin_amdgcn_s_barrier();
    asm volatile("" ::: "memory");

    // ---------------- pipelined K-loop (fully unrolled, compile-time t)
#pragma unroll
    for (int t = 0; t < NT; ++t) {
        if (t + 1 < NT) {
            const int nb = (t + 1) & 1;
#pragma unroll
            for (int s = 0; s < 4; ++s) {
                const int ro = (wv * 32 + s * 8) * 128;
                __builtin_amdgcn_global_load_lds(AS1(A + aSrc0 + s * 8 * K + (t + 1) * 64),
                                                 AS3(smem + nb * 16384 + ro), 16, 0, 0);
                __builtin_amdgcn_global_load_lds(AS1(B + bSrc0 + s * 8 * K + (t + 1) * 64),
                                                 AS3(smem + 32768 + nb * 16384 + ro), 16, 0, 0);
            }
        }
        asm volatile("" ::: "memory");  // pin: pos chunks issue AFTER stage(t+1)
        if constexpr (EPI == 3) {
#pragma unroll
            for (int h = 0; h < 2; ++h) {
                const int i = 2 * t + h;   // compile-time (t unrolled)
                pv[i] = *(const f32x4*)(p00 + (size_t)(i & 3) * 32 * NROWS + (i >> 2) * 32);
            }
        }
        // compute on buf t&1: 2 k-halves x 16 MFMA
#pragma unroll
        for (int kk = 0; kk < 2; ++kk) {
            bf16x8 af[4], bfr[4];
#pragma unroll
            for (int m = 0; m < 4; ++m) {
                const int row = wm * 64 + m * 16 + fr;
                af[m] = *(const bf16x8*)(smem + (t & 1) * 16384 + row * 128 +
                                         (((kk * 4 + fj) ^ (fr & 7)) << 4));
            }
#pragma unroll
            for (int n = 0; n < 4; ++n) {
                const int row = wn * 64 + n * 16 + fr;
                bfr[n] = *(const bf16x8*)(smem + 32768 + (t & 1) * 16384 + row * 128 +
                                          (((kk * 4 + fj) ^ (fr & 7)) << 4));
            }
            __builtin_amdgcn_s_setprio(1);
#pragma unroll
            for (int m = 0; m < 4; ++m)
#pragma unroll
                for (int n = 0; n < 4; ++n)
                    acc[m][n] = __builtin_amdgcn_mfma_f32_16x16x32_bf16(af[m], bfr[n],
                                                                        acc[m][n], 0, 0, 0);
            __builtin_amdgcn_s_setprio(0);
        }
        asm volatile("" ::: "memory");
        if (t + 1 < NT) {
            // EPI3 ledger: [pos(t-1):2][S(t+1):8][pos(t):2] -> vmcnt(2)
            if constexpr (EPI == 3) asm volatile("s_waitcnt vmcnt(2)" ::: "memory");
            else                    asm volatile("s_waitcnt vmcnt(0)" ::: "memory");
        }
        __builtin_amdgcn_s_barrier();
        asm volatile("" ::: "memory");
    }

    if constexpr (EPI == 1 || EPI == 2) {
#pragma unroll
        for (int m = 0; m < 4; ++m) {
            const long rowb = ibase + wm * 64 + m * 16 + crow;
#pragma unroll
            for (int n = 0; n < 4; ++n) {
                const int col = (int)jbase + wn * 64 + n * 16 + ccol;
                const float bv = bias[col];
#pragma unroll
                for (int r = 0; r < 4; ++r) {
                    float v = acc[m][n][r] + bv;
                    const long idx = (rowb + r) * HDIM + col;
                    if constexpr (EPI == 1) {
                        v = v > 0.f ? v : expm1f(v);  // ELU(alpha=1)
                        outb[idx] = (bf16_t)v;
                    } else {
                        outf[idx] = v;
                        outb[idx] = (bf16_t)v;
                    }
                }
            }
        }
    } else {
        // protect staging LDS from e-overwrite while slow waves still read t=7
        __syncthreads();
        // ---- e-materialization: e[row][col] f32 over the 64 KB LDS.
        // Swizzle: 16B chunk (col>>2) ^= row&7 -> balanced banks.
        float* eB = (float*)smem;
#pragma unroll
        for (int mr = 0; mr < 16; ++mr) {
            const int m = mr >> 2, r = mr & 3;
            const int row = wm * 64 + m * 16 + crow + r;   // 0..127
#pragma unroll
            for (int n = 0; n < 4; ++n) {
                const int col = wn * 64 + n * 16 + ccol;   // 0..127
                const float e = exp2f(acc[m][n][r] * r0v[mr] * r1v[n]);
                eB[row * 128 + ((((col >> 2) ^ (row & 7)) << 2) | (col & 3))] = e;
            }
        }
        __syncthreads();
        // ---- reader: chunk i -> row (tid>>3)+32*(i&3), col-chunk (tid&7)+8*(i>>2)
        float S4[4] = {0.f, 0.f, 0.f, 0.f};
        float P4[4] = {0.f, 0.f, 0.f, 0.f};
#pragma unroll
        for (int i = 0; i < 16; ++i) {
            const int r = (tid >> 3) + 32 * (i & 3);
            const int c = (tid & 7) + 8 * (i >> 2);
            const int slot = c ^ (r & 7);
            const f32x4 e4 = *(const f32x4*)&eB[r * 128 + slot * 4];
            S4[i & 3] += e4[0] + e4[1] + e4[2] + e4[3];
            P4[i & 3] += e4[0] * pv[i][0] + e4[1] * pv[i][1] +
                         e4[2] * pv[i][2] + e4[3] * pv[i][3];
        }
#pragma unroll
        for (int a = 0; a < 4; ++a) {
#pragma unroll
            for (int off = 4; off > 0; off >>= 1) {   // reduce 8 consecutive lanes
                S4[a] += __shfl_xor(S4[a], off);
                P4[a] += __shfl_xor(P4[a], off);
            }
        }
        if ((tid & 7) == 0) {
#pragma unroll
            for (int a = 0; a < 4; ++a) {
                const long row = ibase + (tid >> 3) + 32 * a;
                pS[(long)jt * NROWS + row] = S4[a];
                pP[(long)jt * NROWS + row] = P4[a];
            }
        }
    }
}

// ---------------------------------------------------------------- row norms
__global__ __launch_bounds__(256) void rownorm(const bf16_t* __restrict__ Z,
                                               float* __restrict__ rn) {
    const int row  = blockIdx.x * 4 + (threadIdx.x >> 6);
    const int lane = threadIdx.x & 63;
    bf16x8 v = *(const bf16x8*)&Z[(size_t)row * HDIM + lane * 8];
    float s = 0.f;
#pragma unroll
    for (int j = 0; j < 8; ++j) { float f = (float)v[j]; s += f * f; }
#pragma unroll
    for (int off = 32; off > 0; off >>= 1) s += __shfl_xor(s, off);
    if (lane == 0) rn[row] = rsqrtf(s);
}

// ---------------------------------------------------------------- reductions
__global__ __launch_bounds__(256) void reduce_rows(const float* __restrict__ pS,
                                                   const float* __restrict__ pP,
                                                   float* __restrict__ bsum) {
    const int i = blockIdx.x * 256 + threadIdx.x;  // row 0..8191
    float S = 0.f, P = 0.f;
    for (int jb = 0; jb < 64; ++jb) {
        S += pS[jb * NROWS + i];
        P += pP[jb * NROWS + i];
    }
    float t = logf(P / (S + 1e-8f) + 1e-8f);
#pragma unroll
    for (int off = 32; off > 0; off >>= 1) t += __shfl_xor(t, off);
    __shared__ float red[4];
    if ((threadIdx.x & 63) == 0) red[threadIdx.x >> 6] = t;
    __syncthreads();
    if (threadIdx.x == 0) bsum[blockIdx.x] = red[0] + red[1] + red[2] + red[3];
}

__global__ void finalize(const float* __restrict__ bsum, float* __restrict__ loss) {
    float t = (threadIdx.x < 32) ? bsum[threadIdx.x] : 0.f;
#pragma unroll
    for (int off = 32; off > 0; off >>= 1) t += __shfl_xor(t, off);
    if (threadIdx.x == 0) *loss = -(t * (1.0f / 8192.0f));
}

// ---------------------------------------------------------------- launch
extern "C" void kernel_launch(void* const* d_in, const int* in_sizes, int n_in,
                              void* d_out, int out_size, void* d_ws, size_t ws_size,
                              hipStream_t stream) {
    const float* embd0 = (const float*)d_in[0];
    const float* embd1 = (const float*)d_in[1];
    const float* pos   = (const float*)d_in[2];
    const float* W1    = (const float*)d_in[3];
    const float* b1    = (const float*)d_in[4];
    const float* W2    = (const float*)d_in[5];
    const float* b2    = (const float*)d_in[6];
    float* out = (float*)d_out;  // [z0 | z1 | loss]

    char* ws = (char*)d_ws;
    bf16_t* Xb   = (bf16_t*)(ws);               // 16 MB  [16384][512]
    bf16_t* Hb   = (bf16_t*)(ws + 16777216);    // 16 MB
    bf16_t* Zb   = (bf16_t*)(ws + 33554432);    // 16 MB
    bf16_t* W1b  = (bf16_t*)(ws + 50331648);    // 512 KB
    bf16_t* W2b  = (bf16_t*)(ws + 50855936);    // 512 KB
    float*  rn   = (float*)(ws + 51380224);     // 64 KB (rn0|rn1)
    float*  pS   = (float*)(ws + 51445760);     // 2 MB [64][8192]
    float*  pP   = (float*)(ws + 53542912);     // 2 MB
    float*  bsum = (float*)(ws + 55640064);     // 128 B

    cvt_f32_bf16<<<2048, 256, 0, stream>>>(embd0, Xb, 524288);
    cvt_f32_bf16<<<2048, 256, 0, stream>>>(embd1, Xb + 4194304, 524288);
    cvt_f32_bf16<<<128, 256, 0, stream>>>(W1, W1b, 32768);
    cvt_f32_bf16<<<128, 256, 0, stream>>>(W2, W2b, 32768);

    gemm_bt<1><<<dim3(128, 4), 256, 0, stream>>>(Xb, W1b, b1, Hb, nullptr,
                                                 nullptr, nullptr, nullptr, nullptr, nullptr);
    gemm_bt<2><<<dim3(128, 4), 256, 0, stream>>>(Hb, W2b, b2, Zb, out,
                                                 nullptr, nullptr, nullptr, nullptr, nullptr);
    rownorm<<<4096, 256, 0, stream>>>(Zb, rn);
    gemm_bt<3><<<dim3(64, 64), 256, 0, stream>>>(Zb, Zb + 4194304, nullptr,
                                                 nullptr, nullptr, rn, rn + NROWS, pos,
                                                 pS, pP);
    reduce_rows<<<32, 256, 0, stream>>>(pS, pP, bsum);
    finalize<<<1, 64, 0, stream>>>(bsum, out + 8388608);
}